// Round 12
// baseline (33159.448 us; speedup 1.0000x reference)
//
#include <hip/hip_runtime.h>
#include <math.h>
#include <stddef.h>

#define NMOLS 2048
#define MSIZE 50
#define MAXNB 6
#define HD 300
#define NA (NMOLS*MSIZE+1)      /* 102401 atoms incl. zero row 0 */
#define NB (2*NMOLS*MSIZE+1)    /* 204801 bonds incl. zero row 0 */
#define NAM1 (NA-1)             /* 102400 */
#define NPAIR 102400            /* real bond pairs (2r+1, 2r+2) */

// =====================================================================
// Generic GEMM with selectable accumulator type (fp64 for state-path
// noise control): C[row][col] = epi(Arow @ W^T), W row-major [N][K].
// Row map: full = row*RS + RO.
// AMODE 0: A = A0[full*lda + kk]
// AMODE 1: A = MAP[(b2a[full]-1)*300+kk] - MBp[b2revb[full]*300+kk]
// AMODE 2: A = concat(A0[row*300], MAP[row*300], MBp[row*300])  K=900
// Epilogue: optional bias[col], optional CaddF[cidx] (same-element,
// in-place safe), optional relu. cidx = CO + row*ldc + col.
// Tiling: 128x128x8, 256 threads, 8x8 microtile, 8 KB LDS.
// =====================================================================
template<int AMODE, bool BIAS, bool CADD, bool RELU, typename ACC>
__global__ __launch_bounds__(256)
void gemm_k(const float* __restrict__ A0,
            const float* __restrict__ MAP, const float* __restrict__ MBp,
            const int* __restrict__ b2a, const int* __restrict__ b2revb,
            const float* __restrict__ W, const float* __restrict__ bias,
            const float* __restrict__ CaddF, float* __restrict__ C,
            int M, int N, int K, int lda, int RS, int RO, int ldc, int CO)
{
    const int BM = 128, BN = 128, BK = 8;
    __shared__ float As[BK][BM];
    __shared__ float Bs[BK][BN];
    const int bm  = blockIdx.x * BM;
    const int bn  = blockIdx.y * BN;
    const int tid = threadIdx.x;
    const int tx  = tid & 15, ty = tid >> 4;

    ACC acc[8][8];
#pragma unroll
    for (int i = 0; i < 8; i++)
#pragma unroll
        for (int j = 0; j < 8; j++) acc[i][j] = (ACC)0;

    const int lm = tid >> 1;         // 0..127
    const int lk = (tid & 1) * 4;    // 0 or 4

    size_t aoff0 = 0, aoff1 = 0;
    {
        int row = bm + lm;
        if (row < M) {
            int full = row * RS + RO;
            if constexpr (AMODE == 0) {
                aoff0 = (size_t)full * lda;
            } else if constexpr (AMODE == 1) {
                aoff0 = (size_t)(b2a[full] - 1) * HD;
                aoff1 = (size_t)b2revb[full] * HD;
            } else {
                aoff0 = (size_t)row * HD;
            }
        }
    }
    size_t colW = 0;
    {
        int col = bn + lm;
        if (col < N) colW = (size_t)col * K;
    }

    for (int k0 = 0; k0 < K; k0 += BK) {
        {   // ---- stage A ----
            int row = bm + lm;
            float v[4] = {0.f, 0.f, 0.f, 0.f};
            if (row < M) {
#pragma unroll
                for (int j = 0; j < 4; j++) {
                    int kk = k0 + lk + j;
                    if (kk < K) {
                        float x;
                        if constexpr (AMODE == 0) {
                            x = A0[aoff0 + kk];
                        } else if constexpr (AMODE == 1) {
                            x = MAP[aoff0 + kk] - MBp[aoff1 + kk];
                        } else {
                            if (kk < HD)          x = A0 [aoff0 + kk];
                            else if (kk < 2*HD)   x = MAP[aoff0 + kk - HD];
                            else                  x = MBp[aoff0 + kk - 2*HD];
                        }
                        v[j] = x;
                    }
                }
            }
#pragma unroll
            for (int j = 0; j < 4; j++) As[lk + j][lm] = v[j];
        }
        {   // ---- stage B (W[N][K]) ----
            int col = bn + lm;
            float v[4] = {0.f, 0.f, 0.f, 0.f};
            if (col < N) {
#pragma unroll
                for (int j = 0; j < 4; j++) {
                    int kk = k0 + lk + j;
                    if (kk < K) v[j] = W[colW + kk];
                }
            }
#pragma unroll
            for (int j = 0; j < 4; j++) Bs[lk + j][lm] = v[j];
        }
        __syncthreads();
#pragma unroll
        for (int k = 0; k < BK; k++) {
            float a[8], b[8];
#pragma unroll
            for (int i = 0; i < 8; i++) a[i] = As[k][ty * 8 + i];
#pragma unroll
            for (int j = 0; j < 8; j++) b[j] = Bs[k][tx * 8 + j];
#pragma unroll
            for (int i = 0; i < 8; i++)
#pragma unroll
                for (int j = 0; j < 8; j++)
                    acc[i][j] += (ACC)a[i] * (ACC)b[j];
        }
        __syncthreads();
    }

#pragma unroll
    for (int i = 0; i < 8; i++) {
        int row = bm + ty * 8 + i;
        if (row >= M) continue;
#pragma unroll
        for (int j = 0; j < 8; j++) {
            int col = bn + tx * 8 + j;
            if (col >= N) continue;
            float v = (float)acc[i][j];
            if constexpr (BIAS) v += bias[col];
            size_t cidx = (size_t)CO + (size_t)row * ldc + col;
            if constexpr (CADD) v += CaddF[cidx];
            if constexpr (RELU) v = fmaxf(v, 0.f);
            C[cidx] = v;
        }
    }
}

// =====================================================================
// Aggregation for atoms atom0..: s=sum (j order matches np), m=max over
// MAXNB gathered bond rows; out = s*m (+addsrc, same-element safe).
// =====================================================================
__global__ __launch_bounds__(256)
void agg_k(const float* __restrict__ mb, const int* __restrict__ a2b,
           const float* __restrict__ addsrc, float* __restrict__ out,
           int atom0, int total)
{
    int idx = blockIdx.x * 256 + threadIdx.x;
    if (idx >= total) return;
    int l = idx / HD;
    int h = idx - l * HD;
    const int* nb = a2b + (size_t)(atom0 + l) * MAXNB;
    float s = 0.f, m = -INFINITY;
#pragma unroll
    for (int j = 0; j < MAXNB; j++) {
        float v = mb[(size_t)nb[j] * HD + h];
        s += v;
        m = fmaxf(m, v);
    }
    float r = s * m;
    if (addsrc) r += addsrc[idx];
    out[idx] = r;
}

// P3: commit TMP pair-results into odd rows of MB.
__global__ __launch_bounds__(256)
void copy_odd_k(const float* __restrict__ tmp, float* __restrict__ mb)
{
    int idx = blockIdx.x * 256 + threadIdx.x;
    if (idx >= NPAIR * HD) return;
    int r = idx / HD, c = idx - r * HD;
    mb[(size_t)r * 600 + HD + c] = tmp[idx];   // row 2r+1
}

// msg = relu(node + gru_bias)
__global__ __launch_bounds__(256)
void msg_k(const float* __restrict__ node, const float* __restrict__ gb,
           float* __restrict__ msg, int total)
{
    int idx = blockIdx.x * 256 + threadIdx.x;
    if (idx >= total) return;
    msg[idx] = fmaxf(node[idx] + gb[idx % HD], 0.f);
}

// h0[mol][h] = max_t node[mol*50+t][h]  (pre-relu node, atoms 1..)
__global__ __launch_bounds__(256)
void h0_k(const float* __restrict__ node, float* __restrict__ h0)
{
    int idx = blockIdx.x * 256 + threadIdx.x;
    if (idx >= NMOLS * HD) return;
    int mol = idx / HD, h = idx - mol * HD;
    const float* p = node + (size_t)mol * MSIZE * HD + h;
    float m = -INFINITY;
#pragma unroll 5
    for (int t = 0; t < MSIZE; t++) m = fmaxf(m, p[(size_t)t * HD]);
    h0[idx] = m;
}

// =====================================================================
// Fused GRU (gi + gh matvecs in-kernel, fp64 accumulators). One
// direction per launch; 8 mols/block, 256 thr, 57.6 KB LDS.
// gout: fp32 [row][600], column block dir*300.
// =====================================================================
__global__ __launch_bounds__(256)
void gru_k(const float* __restrict__ msg, const float* __restrict__ wih,
           const float* __restrict__ whh, const float* __restrict__ bih,
           const float* __restrict__ bhh, const float* __restrict__ h0,
           float* __restrict__ gout, int dir)
{
    __shared__ float hs[8][HD];          // 9.6 KB
    __shared__ float ms[8][HD];          // 9.6 KB
    __shared__ float F [8][2 * HD];      // 19.2 KB (r,z pre-activations)
    __shared__ float INg[8][HD];         // 9.6 KB
    __shared__ float HNg[8][HD];         // 9.6 KB
    const int m0  = blockIdx.x * 8;
    const int tid = threadIdx.x;
    const float* wi = wih + (size_t)dir * 900 * HD;
    const float* wh = whh + (size_t)dir * 900 * HD;
    const float* bi = bih + dir * 900;
    const float* bh = bhh + dir * 900;

    for (int e = tid; e < 8 * HD; e += 256) {
        int mm = e / HD, h = e - mm * HD;
        hs[mm][h] = h0[(size_t)(m0 + mm) * HD + h];
    }
    __syncthreads();

    for (int t = 0; t < MSIZE; t++) {
        int ta = dir ? (MSIZE - 1 - t) : t;
        for (int e = tid; e < 8 * HD; e += 256) {
            int mm = e / HD, h = e - mm * HD;
            ms[mm][h] = msg[((size_t)(m0 + mm) * MSIZE + ta) * HD + h];
        }
        __syncthreads();
        for (int n = tid; n < 900; n += 256) {
            const float* wir = wi + (size_t)n * HD;
            const float* whr = wh + (size_t)n * HD;
            double ai[8], ah[8];
            double bin = (double)bi[n], bhn = (double)bh[n];
#pragma unroll
            for (int mm = 0; mm < 8; mm++) { ai[mm] = bin; ah[mm] = bhn; }
            for (int k = 0; k < HD; k += 4) {
                float4 w4 = *(const float4*)(wir + k);
                float4 v4 = *(const float4*)(whr + k);
#pragma unroll
                for (int mm = 0; mm < 8; mm++) {
                    ai[mm] += (double)ms[mm][k]   * (double)w4.x
                            + (double)ms[mm][k+1] * (double)w4.y
                            + (double)ms[mm][k+2] * (double)w4.z
                            + (double)ms[mm][k+3] * (double)w4.w;
                    ah[mm] += (double)hs[mm][k]   * (double)v4.x
                            + (double)hs[mm][k+1] * (double)v4.y
                            + (double)hs[mm][k+2] * (double)v4.z
                            + (double)hs[mm][k+3] * (double)v4.w;
                }
            }
            if (n < 2 * HD) {
#pragma unroll
                for (int mm = 0; mm < 8; mm++) F[mm][n] = (float)(ai[mm] + ah[mm]);
            } else {
#pragma unroll
                for (int mm = 0; mm < 8; mm++) {
                    INg[mm][n - 2 * HD] = (float)ai[mm];
                    HNg[mm][n - 2 * HD] = (float)ah[mm];
                }
            }
        }
        __syncthreads();
        for (int e = tid; e < 8 * HD; e += 256) {
            int mm = e / HD, h = e - mm * HD;
            float r  = 1.f / (1.f + expf(-F[mm][h]));
            float z  = 1.f / (1.f + expf(-F[mm][HD + h]));
            float nn = tanhf(INg[mm][h] + r * HNg[mm][h]);
            float hv = (1.f - z) * nn + z * hs[mm][h];
            hs[mm][h] = hv;
            gout[((size_t)(m0 + mm) * MSIZE + ta) * 600 + (size_t)dir * HD + h] = hv;
        }
        __syncthreads();
    }
}

// ws-too-small sentinel: absmax ~3.4e38, distinct from all-zeros 1.33e15.
__global__ void sentinel_k(unsigned int* p) { p[0] = 0x7F7F7F7Fu; }

// =====================================================================
extern "C" void kernel_launch(void* const* d_in, const int* in_sizes, int n_in,
                              void* d_out, int out_size, void* d_ws, size_t ws_size,
                              hipStream_t stream)
{
    const float* f_atoms  = (const float*)d_in[0];
    const float* f_bonds  = (const float*)d_in[1];
    const float* Wi_atom  = (const float*)d_in[2];
    const float* Wi_bond  = (const float*)d_in[3];
    const float* Wh       = (const float*)d_in[4];
    const float* W_lr     = (const float*)d_in[5];
    const float* Wo_w     = (const float*)d_in[6];
    const float* Wo_b     = (const float*)d_in[7];
    const float* gru_bias = (const float*)d_in[8];
    const float* wih      = (const float*)d_in[9];
    const float* whh      = (const float*)d_in[10];
    const float* bih      = (const float*)d_in[11];
    const float* bhh      = (const float*)d_in[12];
    const int*   a2b      = (const int*)d_in[13];
    const int*   b2a      = (const int*)d_in[14];
    const int*   b2revb   = (const int*)d_in[15];
    (void)in_sizes; (void)n_in; (void)out_size;

    const size_t SB = (size_t)NB * HD;      // 61,440,300
    const size_t SN = (size_t)NAM1 * HD;    // 30,720,000

    // ws (floats): MB [0,SB) | TMP [SB, SB+SN).  NEED = 368.6 MB (proven fit).
    // Phase 2 aliases: SM->TMP; IA->MB[0,SN); NODE->MB[SN,2SN) (2SN<=SB);
    // H0->TMP[0,0.62M); GOUT fp32 [NAM1*600=61.44M]->MB[0,..) after NODE read.
    // MA / MSG / OUT live in d_out (SN fp32, rewritten every call).
    const size_t NEED = (SB + SN) * sizeof(float);
    if (ws_size < NEED) {
        sentinel_k<<<1, 1, 0, stream>>>((unsigned int*)d_out);
        return;
    }

    float* MB   = (float*)d_ws;
    float* TMP  = MB + SB;
    float* MA   = (float*)d_out;
    float* SM   = TMP;
    float* IA   = MB;
    float* NODE = MB + SN;
    float* H0   = TMP;
    float* GOUT = MB;
    float* MSG  = (float*)d_out;
    float* OUT  = (float*)d_out;

    auto gg = [](int m, int n) { return dim3((unsigned)((m + 127) / 128),
                                             (unsigned)((n + 127) / 128)); };
    const int aggblocks = (int)((SN + 255) / 256);

    // 1: mb = relu(f_bonds @ Wi_bond^T), all NB rows (row 0 stays 0)
    gemm_k<0,false,false,true,double><<<gg(NB, HD), 256, 0, stream>>>(
        f_bonds, nullptr, nullptr, nullptr, nullptr,
        Wi_bond, nullptr, nullptr, MB, NB, HD, 147, 147, 1, 0, HD, 0);

    // 2: message_atom (atoms 1..) = relu(f_atoms @ Wi_atom^T) -> d_out
    gemm_k<0,false,false,true,double><<<gg(NAM1, HD), 256, 0, stream>>>(
        f_atoms, nullptr, nullptr, nullptr, nullptr,
        Wi_atom, nullptr, nullptr, MA, NAM1, HD, 133, 133, 1, 1, HD, 0);

    // 3: depth loop (5 iters), in-place mb via bond-pair structure
    for (int d = 0; d < 5; d++) {
        const float* Whd = Wh + (size_t)d * HD * HD;
        // a. ma += s*m
        agg_k<<<aggblocks, 256, 0, stream>>>(MB, a2b, MA, MA, 1, (int)SN);
        // b. P1a: TMP = relu(ib_odd)            (rows 2r+1)
        gemm_k<0,false,false,true,double><<<gg(NPAIR, HD), 256, 0, stream>>>(
            f_bonds, nullptr, nullptr, nullptr, nullptr,
            Wi_bond, nullptr, nullptr, TMP, NPAIR, HD, 147, 147, 2, 1, HD, 0);
        // c. P1b: TMP = relu(TMP + (ma[b2a]-mb[rev])@Wh^T)   (reads even mb)
        gemm_k<1,false,true,true,double><<<gg(NPAIR, HD), 256, 0, stream>>>(
            nullptr, MA, MB, b2a, b2revb,
            Whd, nullptr, TMP, TMP, NPAIR, HD, HD, HD, 2, 1, HD, 0);
        // d. P2a: mb[even] = relu(ib_even)      (old even dead)
        gemm_k<0,false,false,true,double><<<gg(NPAIR, HD), 256, 0, stream>>>(
            f_bonds, nullptr, nullptr, nullptr, nullptr,
            Wi_bond, nullptr, nullptr, MB, NPAIR, HD, 147, 147, 2, 2, 600, 600);
        // e. P2b: mb[even] = relu(mb[even] + (ma[b2a]-mb[odd])@Wh^T)
        gemm_k<1,false,true,true,double><<<gg(NPAIR, HD), 256, 0, stream>>>(
            nullptr, MA, MB, b2a, b2revb,
            Whd, nullptr, MB, MB, NPAIR, HD, HD, HD, 2, 2, 600, 600);
        // f. P3: mb[odd] = TMP
        copy_odd_k<<<(int)((SN + 255) / 256), 256, 0, stream>>>(TMP, MB);
    }

    // 4: final s*m -> SM (TMP); mb dead after this
    agg_k<<<aggblocks, 256, 0, stream>>>(MB, a2b, nullptr, SM, 1, (int)SN);

    // 5: IA = relu(f_atoms @ Wi_atom^T) -> MB[0,SN)
    gemm_k<0,false,false,true,double><<<gg(NAM1, HD), 256, 0, stream>>>(
        f_atoms, nullptr, nullptr, nullptr, nullptr,
        Wi_atom, nullptr, nullptr, IA, NAM1, HD, 133, 133, 1, 1, HD, 0);

    // 6: node = concat(sm, ma, ia) @ W_lr^T -> NODE (MB[SN,2SN))
    gemm_k<2,false,false,false,double><<<gg(NAM1, HD), 256, 0, stream>>>(
        SM, MA, IA, nullptr, nullptr,
        W_lr, nullptr, nullptr, NODE, NAM1, HD, 900, HD, 1, 0, HD, 0);

    // 7-8: msg = relu(node+gru_bias) -> d_out (MA dead); h0 -> TMP (SM dead)
    msg_k<<<aggblocks, 256, 0, stream>>>(NODE, gru_bias, MSG, (int)SN);
    h0_k<<<(NMOLS * HD + 255) / 256, 256, 0, stream>>>(NODE, H0);

    // 9-10: fused GRU, both dirs -> GOUT fp32 over MB (IA/NODE dead)
    gru_k<<<NMOLS / 8, 256, 0, stream>>>(MSG, wih, whh, bih, bhh, H0, GOUT, 0);
    gru_k<<<NMOLS / 8, 256, 0, stream>>>(MSG, wih, whh, bih, bhh, H0, GOUT, 1);

    // 11: atom_hiddens = relu(GOUT @ Wo_w^T + Wo_b) -> d_out (MSG dead)
    gemm_k<0,true,false,true,double><<<gg(NAM1, HD), 256, 0, stream>>>(
        GOUT, nullptr, nullptr, nullptr, nullptr,
        Wo_w, Wo_b, nullptr, OUT, NAM1, HD, 600, 600, 1, 0, HD, 0);
}

// Round 13
// 32399.570 us; speedup vs baseline: 1.0235x; 1.0235x over previous
//
#include <hip/hip_runtime.h>
#include <math.h>
#include <stddef.h>

#define NMOLS 2048
#define MSIZE 50
#define MAXNB 6
#define HD 300
#define NA (NMOLS*MSIZE+1)      /* 102401 atoms incl. zero row 0 */
#define NB (2*NMOLS*MSIZE+1)    /* 204801 bonds incl. zero row 0 */
#define NAM1 (NA-1)             /* 102400 */
#define NPAIR 102400            /* real bond pairs (2r+1, 2r+2) */

// =====================================================================
// Generic GEMM with fp64 accumulators (state-path noise control):
// C[row][col] = epi(Arow @ W^T), W row-major [N][K].  full = row*RS+RO.
// AMODE 0: A = A0[full*lda + kk]
// AMODE 1: A = MAP[(b2a[full]-1)*300+kk] - MBp[b2revb[full]*300+kk]
// AMODE 2: A = concat(A0[row*300], MAP[row*300], MBp[row*300])  K=900
// Epilogue: optional bias[col], optional CaddF[cidx] (same-element,
// in-place safe), optional relu. cidx = CO + row*ldc + col.
// Tiling: 128x128x8, 256 threads, 8x8 microtile, 8 KB LDS.
// Inner-loop LDS reads vectorized to float4 (ds_read_b128).
// =====================================================================
template<int AMODE, bool BIAS, bool CADD, bool RELU, typename ACC>
__global__ __launch_bounds__(256)
void gemm_k(const float* __restrict__ A0,
            const float* __restrict__ MAP, const float* __restrict__ MBp,
            const int* __restrict__ b2a, const int* __restrict__ b2revb,
            const float* __restrict__ W, const float* __restrict__ bias,
            const float* __restrict__ CaddF, float* __restrict__ C,
            int M, int N, int K, int lda, int RS, int RO, int ldc, int CO)
{
    const int BM = 128, BN = 128, BK = 8;
    __shared__ float As[BK][BM];
    __shared__ float Bs[BK][BN];
    const int bm  = blockIdx.x * BM;
    const int bn  = blockIdx.y * BN;
    const int tid = threadIdx.x;
    const int tx  = tid & 15, ty = tid >> 4;

    ACC acc[8][8];
#pragma unroll
    for (int i = 0; i < 8; i++)
#pragma unroll
        for (int j = 0; j < 8; j++) acc[i][j] = (ACC)0;

    const int lm = tid >> 1;         // 0..127
    const int lk = (tid & 1) * 4;    // 0 or 4

    size_t aoff0 = 0, aoff1 = 0;
    {
        int row = bm + lm;
        if (row < M) {
            int full = row * RS + RO;
            if constexpr (AMODE == 0) {
                aoff0 = (size_t)full * lda;
            } else if constexpr (AMODE == 1) {
                aoff0 = (size_t)(b2a[full] - 1) * HD;
                aoff1 = (size_t)b2revb[full] * HD;
            } else {
                aoff0 = (size_t)row * HD;
            }
        }
    }
    size_t colW = 0;
    {
        int col = bn + lm;
        if (col < N) colW = (size_t)col * K;
    }

    for (int k0 = 0; k0 < K; k0 += BK) {
        {   // ---- stage A ----
            int row = bm + lm;
            float v[4] = {0.f, 0.f, 0.f, 0.f};
            if (row < M) {
#pragma unroll
                for (int j = 0; j < 4; j++) {
                    int kk = k0 + lk + j;
                    if (kk < K) {
                        float x;
                        if constexpr (AMODE == 0) {
                            x = A0[aoff0 + kk];
                        } else if constexpr (AMODE == 1) {
                            x = MAP[aoff0 + kk] - MBp[aoff1 + kk];
                        } else {
                            if (kk < HD)          x = A0 [aoff0 + kk];
                            else if (kk < 2*HD)   x = MAP[aoff0 + kk - HD];
                            else                  x = MBp[aoff0 + kk - 2*HD];
                        }
                        v[j] = x;
                    }
                }
            }
#pragma unroll
            for (int j = 0; j < 4; j++) As[lk + j][lm] = v[j];
        }
        {   // ---- stage B (W[N][K]) ----
            int col = bn + lm;
            float v[4] = {0.f, 0.f, 0.f, 0.f};
            if (col < N) {
#pragma unroll
                for (int j = 0; j < 4; j++) {
                    int kk = k0 + lk + j;
                    if (kk < K) v[j] = W[colW + kk];
                }
            }
#pragma unroll
            for (int j = 0; j < 4; j++) Bs[lk + j][lm] = v[j];
        }
        __syncthreads();
#pragma unroll
        for (int k = 0; k < BK; k++) {
            // vectorized LDS reads: 2x float4 per operand row
            float4 a0 = *(const float4*)&As[k][ty * 8];
            float4 a1 = *(const float4*)&As[k][ty * 8 + 4];
            float4 b0 = *(const float4*)&Bs[k][tx * 8];
            float4 b1 = *(const float4*)&Bs[k][tx * 8 + 4];
            float a[8] = {a0.x, a0.y, a0.z, a0.w, a1.x, a1.y, a1.z, a1.w};
            float b[8] = {b0.x, b0.y, b0.z, b0.w, b1.x, b1.y, b1.z, b1.w};
#pragma unroll
            for (int i = 0; i < 8; i++)
#pragma unroll
                for (int j = 0; j < 8; j++)
                    acc[i][j] += (ACC)a[i] * (ACC)b[j];
        }
        __syncthreads();
    }

#pragma unroll
    for (int i = 0; i < 8; i++) {
        int row = bm + ty * 8 + i;
        if (row >= M) continue;
#pragma unroll
        for (int j = 0; j < 8; j++) {
            int col = bn + tx * 8 + j;
            if (col >= N) continue;
            float v = (float)acc[i][j];
            if constexpr (BIAS) v += bias[col];
            size_t cidx = (size_t)CO + (size_t)row * ldc + col;
            if constexpr (CADD) v += CaddF[cidx];
            if constexpr (RELU) v = fmaxf(v, 0.f);
            C[cidx] = v;
        }
    }
}

// =====================================================================
// Aggregation for atoms atom0..: s=sum (j order matches np), m=max over
// MAXNB gathered bond rows; out = s*m (+addsrc, same-element safe).
// =====================================================================
__global__ __launch_bounds__(256)
void agg_k(const float* __restrict__ mb, const int* __restrict__ a2b,
           const float* __restrict__ addsrc, float* __restrict__ out,
           int atom0, int total)
{
    int idx = blockIdx.x * 256 + threadIdx.x;
    if (idx >= total) return;
    int l = idx / HD;
    int h = idx - l * HD;
    const int* nb = a2b + (size_t)(atom0 + l) * MAXNB;
    float s = 0.f, m = -INFINITY;
#pragma unroll
    for (int j = 0; j < MAXNB; j++) {
        float v = mb[(size_t)nb[j] * HD + h];
        s += v;
        m = fmaxf(m, v);
    }
    float r = s * m;
    if (addsrc) r += addsrc[idx];
    out[idx] = r;
}

// P3: commit TMP pair-results into odd rows of MB.
__global__ __launch_bounds__(256)
void copy_odd_k(const float* __restrict__ tmp, float* __restrict__ mb)
{
    int idx = blockIdx.x * 256 + threadIdx.x;
    if (idx >= NPAIR * HD) return;
    int r = idx / HD, c = idx - r * HD;
    mb[(size_t)r * 600 + HD + c] = tmp[idx];   // row 2r+1
}

// msg = relu(node + gru_bias)
__global__ __launch_bounds__(256)
void msg_k(const float* __restrict__ node, const float* __restrict__ gb,
           float* __restrict__ msg, int total)
{
    int idx = blockIdx.x * 256 + threadIdx.x;
    if (idx >= total) return;
    msg[idx] = fmaxf(node[idx] + gb[idx % HD], 0.f);
}

// h0[mol][h] = max_t node[mol*50+t][h]  (pre-relu node, atoms 1..)
__global__ __launch_bounds__(256)
void h0_k(const float* __restrict__ node, float* __restrict__ h0)
{
    int idx = blockIdx.x * 256 + threadIdx.x;
    if (idx >= NMOLS * HD) return;
    int mol = idx / HD, h = idx - mol * HD;
    const float* p = node + (size_t)mol * MSIZE * HD + h;
    float m = -INFINITY;
#pragma unroll 5
    for (int t = 0; t < MSIZE; t++) m = fmaxf(m, p[(size_t)t * HD]);
    h0[idx] = m;
}

// =====================================================================
// Fused GRU (gi + gh matvecs in-kernel, fp64 accumulators). BOTH
// directions in one launch: grid (NMOLS/8, 2), blockIdx.y = dir.
// 512 blocks -> 2 blocks/CU (LDS 57.6 KB x2 = 115.2 <= 160 KB).
// ms/hs consumed as aligned float4 (ds_read_b128 broadcast).
// gout: fp32 [row][600], column block dir*300.
// =====================================================================
__global__ __launch_bounds__(256)
void gru_k(const float* __restrict__ msg, const float* __restrict__ wih,
           const float* __restrict__ whh, const float* __restrict__ bih,
           const float* __restrict__ bhh, const float* __restrict__ h0,
           float* __restrict__ gout)
{
    __shared__ float hs[8][HD];          // 9.6 KB
    __shared__ float ms[8][HD];          // 9.6 KB
    __shared__ float F [8][2 * HD];      // 19.2 KB (r,z pre-activations)
    __shared__ float INg[8][HD];         // 9.6 KB
    __shared__ float HNg[8][HD];         // 9.6 KB
    const int dir = blockIdx.y;
    const int m0  = blockIdx.x * 8;
    const int tid = threadIdx.x;
    const float* wi = wih + (size_t)dir * 900 * HD;
    const float* wh = whh + (size_t)dir * 900 * HD;
    const float* bi = bih + dir * 900;
    const float* bh = bhh + dir * 900;

    for (int e = tid; e < 8 * HD; e += 256) {
        int mm = e / HD, h = e - mm * HD;
        hs[mm][h] = h0[(size_t)(m0 + mm) * HD + h];
    }
    __syncthreads();

    for (int t = 0; t < MSIZE; t++) {
        int ta = dir ? (MSIZE - 1 - t) : t;
        for (int e = tid; e < 8 * HD; e += 256) {
            int mm = e / HD, h = e - mm * HD;
            ms[mm][h] = msg[((size_t)(m0 + mm) * MSIZE + ta) * HD + h];
        }
        __syncthreads();
        for (int n = tid; n < 900; n += 256) {
            const float* wir = wi + (size_t)n * HD;
            const float* whr = wh + (size_t)n * HD;
            double ai[8], ah[8];
            double bin = (double)bi[n], bhn = (double)bh[n];
#pragma unroll
            for (int mm = 0; mm < 8; mm++) { ai[mm] = bin; ah[mm] = bhn; }
            for (int k = 0; k < HD; k += 4) {
                float4 w4 = *(const float4*)(wir + k);
                float4 v4 = *(const float4*)(whr + k);
#pragma unroll
                for (int mm = 0; mm < 8; mm++) {
                    float4 m4 = *(const float4*)(&ms[mm][k]);   // ds_read_b128
                    float4 h4 = *(const float4*)(&hs[mm][k]);   // ds_read_b128
                    ai[mm] += (double)m4.x * (double)w4.x
                            + (double)m4.y * (double)w4.y
                            + (double)m4.z * (double)w4.z
                            + (double)m4.w * (double)w4.w;
                    ah[mm] += (double)h4.x * (double)v4.x
                            + (double)h4.y * (double)v4.y
                            + (double)h4.z * (double)v4.z
                            + (double)h4.w * (double)v4.w;
                }
            }
            if (n < 2 * HD) {
#pragma unroll
                for (int mm = 0; mm < 8; mm++) F[mm][n] = (float)(ai[mm] + ah[mm]);
            } else {
#pragma unroll
                for (int mm = 0; mm < 8; mm++) {
                    INg[mm][n - 2 * HD] = (float)ai[mm];
                    HNg[mm][n - 2 * HD] = (float)ah[mm];
                }
            }
        }
        __syncthreads();
        for (int e = tid; e < 8 * HD; e += 256) {
            int mm = e / HD, h = e - mm * HD;
            float r  = 1.f / (1.f + expf(-F[mm][h]));
            float z  = 1.f / (1.f + expf(-F[mm][HD + h]));
            float nn = tanhf(INg[mm][h] + r * HNg[mm][h]);
            float hv = (1.f - z) * nn + z * hs[mm][h];
            hs[mm][h] = hv;
            gout[((size_t)(m0 + mm) * MSIZE + ta) * 600 + (size_t)dir * HD + h] = hv;
        }
        __syncthreads();
    }
}

// ws-too-small sentinel: absmax ~3.4e38, distinct from all-zeros 1.33e15.
__global__ void sentinel_k(unsigned int* p) { p[0] = 0x7F7F7F7Fu; }

// =====================================================================
extern "C" void kernel_launch(void* const* d_in, const int* in_sizes, int n_in,
                              void* d_out, int out_size, void* d_ws, size_t ws_size,
                              hipStream_t stream)
{
    const float* f_atoms  = (const float*)d_in[0];
    const float* f_bonds  = (const float*)d_in[1];
    const float* Wi_atom  = (const float*)d_in[2];
    const float* Wi_bond  = (const float*)d_in[3];
    const float* Wh       = (const float*)d_in[4];
    const float* W_lr     = (const float*)d_in[5];
    const float* Wo_w     = (const float*)d_in[6];
    const float* Wo_b     = (const float*)d_in[7];
    const float* gru_bias = (const float*)d_in[8];
    const float* wih      = (const float*)d_in[9];
    const float* whh      = (const float*)d_in[10];
    const float* bih      = (const float*)d_in[11];
    const float* bhh      = (const float*)d_in[12];
    const int*   a2b      = (const int*)d_in[13];
    const int*   b2a      = (const int*)d_in[14];
    const int*   b2revb   = (const int*)d_in[15];
    (void)in_sizes; (void)n_in; (void)out_size;

    const size_t SB = (size_t)NB * HD;      // 61,440,300
    const size_t SN = (size_t)NAM1 * HD;    // 30,720,000

    // ws (floats): MB [0,SB) | TMP [SB, SB+SN).  NEED = 368.6 MB (proven fit).
    // Phase 2 aliases: SM->TMP; IA->MB[0,SN); NODE->MB[SN,2SN) (2SN<=SB);
    // H0->TMP[0,0.62M); GOUT fp32 [NAM1*600=61.44M]->MB[0,..) after NODE read.
    // MA / MSG / OUT live in d_out (SN fp32, rewritten every call).
    const size_t NEED = (SB + SN) * sizeof(float);
    if (ws_size < NEED) {
        sentinel_k<<<1, 1, 0, stream>>>((unsigned int*)d_out);
        return;
    }

    float* MB   = (float*)d_ws;
    float* TMP  = MB + SB;
    float* MA   = (float*)d_out;
    float* SM   = TMP;
    float* IA   = MB;
    float* NODE = MB + SN;
    float* H0   = TMP;
    float* GOUT = MB;
    float* MSG  = (float*)d_out;
    float* OUT  = (float*)d_out;

    auto gg = [](int m, int n) { return dim3((unsigned)((m + 127) / 128),
                                             (unsigned)((n + 127) / 128)); };
    const int aggblocks = (int)((SN + 255) / 256);

    // 1: mb = relu(f_bonds @ Wi_bond^T), all NB rows (row 0 stays 0)
    gemm_k<0,false,false,true,double><<<gg(NB, HD), 256, 0, stream>>>(
        f_bonds, nullptr, nullptr, nullptr, nullptr,
        Wi_bond, nullptr, nullptr, MB, NB, HD, 147, 147, 1, 0, HD, 0);

    // 2: message_atom (atoms 1..) = relu(f_atoms @ Wi_atom^T) -> d_out
    gemm_k<0,false,false,true,double><<<gg(NAM1, HD), 256, 0, stream>>>(
        f_atoms, nullptr, nullptr, nullptr, nullptr,
        Wi_atom, nullptr, nullptr, MA, NAM1, HD, 133, 133, 1, 1, HD, 0);

    // 3: depth loop (5 iters), in-place mb via bond-pair structure
    for (int d = 0; d < 5; d++) {
        const float* Whd = Wh + (size_t)d * HD * HD;
        // a. ma += s*m
        agg_k<<<aggblocks, 256, 0, stream>>>(MB, a2b, MA, MA, 1, (int)SN);
        // b. P1a: TMP = relu(ib_odd)            (rows 2r+1)
        gemm_k<0,false,false,true,double><<<gg(NPAIR, HD), 256, 0, stream>>>(
            f_bonds, nullptr, nullptr, nullptr, nullptr,
            Wi_bond, nullptr, nullptr, TMP, NPAIR, HD, 147, 147, 2, 1, HD, 0);
        // c. P1b: TMP = relu(TMP + (ma[b2a]-mb[rev])@Wh^T)   (reads even mb)
        gemm_k<1,false,true,true,double><<<gg(NPAIR, HD), 256, 0, stream>>>(
            nullptr, MA, MB, b2a, b2revb,
            Whd, nullptr, TMP, TMP, NPAIR, HD, HD, HD, 2, 1, HD, 0);
        // d. P2a: mb[even] = relu(ib_even)      (old even dead)
        gemm_k<0,false,false,true,double><<<gg(NPAIR, HD), 256, 0, stream>>>(
            f_bonds, nullptr, nullptr, nullptr, nullptr,
            Wi_bond, nullptr, nullptr, MB, NPAIR, HD, 147, 147, 2, 2, 600, 600);
        // e. P2b: mb[even] = relu(mb[even] + (ma[b2a]-mb[odd])@Wh^T)
        gemm_k<1,false,true,true,double><<<gg(NPAIR, HD), 256, 0, stream>>>(
            nullptr, MA, MB, b2a, b2revb,
            Whd, nullptr, MB, MB, NPAIR, HD, HD, HD, 2, 2, 600, 600);
        // f. P3: mb[odd] = TMP
        copy_odd_k<<<(int)((SN + 255) / 256), 256, 0, stream>>>(TMP, MB);
    }

    // 4: final s*m -> SM (TMP); mb dead after this
    agg_k<<<aggblocks, 256, 0, stream>>>(MB, a2b, nullptr, SM, 1, (int)SN);

    // 5: IA = relu(f_atoms @ Wi_atom^T) -> MB[0,SN)
    gemm_k<0,false,false,true,double><<<gg(NAM1, HD), 256, 0, stream>>>(
        f_atoms, nullptr, nullptr, nullptr, nullptr,
        Wi_atom, nullptr, nullptr, IA, NAM1, HD, 133, 133, 1, 1, HD, 0);

    // 6: node = concat(sm, ma, ia) @ W_lr^T -> NODE (MB[SN,2SN))
    gemm_k<2,false,false,false,double><<<gg(NAM1, HD), 256, 0, stream>>>(
        SM, MA, IA, nullptr, nullptr,
        W_lr, nullptr, nullptr, NODE, NAM1, HD, 900, HD, 1, 0, HD, 0);

    // 7-8: msg = relu(node+gru_bias) -> d_out (MA dead); h0 -> TMP (SM dead)
    msg_k<<<aggblocks, 256, 0, stream>>>(NODE, gru_bias, MSG, (int)SN);
    h0_k<<<(NMOLS * HD + 255) / 256, 256, 0, stream>>>(NODE, H0);

    // 9: fused GRU, BOTH dirs in one launch -> GOUT fp32 over MB
    gru_k<<<dim3(NMOLS / 8, 2), 256, 0, stream>>>(MSG, wih, whh, bih, bhh, H0, GOUT);

    // 10: atom_hiddens = relu(GOUT @ Wo_w^T + Wo_b) -> d_out (MSG dead)
    gemm_k<0,true,false,true,double><<<gg(NAM1, HD), 256, 0, stream>>>(
        GOUT, nullptr, nullptr, nullptr, nullptr,
        Wo_w, Wo_b, nullptr, OUT, NAM1, HD, 600, 600, 1, 0, HD, 0);
}